// Round 1
// 116.515 us; speedup vs baseline: 1.0628x; 1.0628x over previous
//
#include <hip/hip_runtime.h>

// MpMaxPoolingMatch: out[b,t,m] = tanh( max_s sum_d lt[b,t,d]*km[m,d]*rt[b,s,d] )
// B=32, T=256, D=512, MP=20.
// R11: attack the stall, not the floor. R10 measured 54us with MfmaUtil 14.7%
// (= exactly the 9.2us MFMA floor worth of busy cycles) and Occupancy 25%
// (2 waves/SIMD: unified regfile ~256/wave from 128 regs of A/B double-buffers).
// Changes vs R10:
//  * rtf is now written TILED by the cast kernel: [b][kk(4)][g16(16)][h(2)][lane(64)][16B]
//    = exact MFMA B-fragment order. Main kernel stages B via global_load_lds
//    (async DMA, LDS dst = uniform base + lane*16) -> zero VALU, zero VGPR, and
//    ds_read_b128 at lane*16 stride -> conflict-free by construction.
//  * Wave self-service: wave w stages only its own s-rows (g'=w) -> NO barriers
//    in the K-loop. Double-buffered 8KB s=64 slices, 16 steps, counted
//    s_waitcnt vmcnt(2) (never 0 in-loop; T4 discipline).
//  * Registers: b0/b1 reg-buffers gone (-64), A-frags single-buffered per kk.
//    LDS = 33.8K (Ash, unchanged) + 16K (B dbuf) + 1K = 51.2KB -> 3 blocks/CU,
//    12 waves/CU (was 8).
// A-conversion path, MFMA byte order, scales (e8m0=127), epilogue: identical to R10.

constexpr int TT = 256;   // T
constexpr int DD = 512;   // D
constexpr int NM = 20;    // MP
constexpr int NB = 32;    // B
constexpr int BM = 64;    // t-tile

typedef float f32x4 __attribute__((ext_vector_type(4)));
typedef int   i32x8 __attribute__((ext_vector_type(8)));

__device__ __forceinline__ unsigned pack_bf16(float lo, float hi) {
    unsigned ulo = __builtin_bit_cast(unsigned, lo);
    unsigned uhi = __builtin_bit_cast(unsigned, hi);
    return (ulo >> 16) | (uhi & 0xFFFF0000u);
}

// 4 fp32 -> 4 fp8 (e4m3, packed dword)
__device__ __forceinline__ unsigned pk4_fp8(float a, float b, float c, float d) {
    unsigned r = __builtin_amdgcn_cvt_pk_fp8_f32(a, b, 0, false);
    return __builtin_amdgcn_cvt_pk_fp8_f32(c, d, r, true);
}

__device__ __forceinline__ float blo(unsigned u) { return __builtin_bit_cast(float, u << 16); }
// hi bf16 without masking low bits: <0.4% perturbation, absorbed by fp8 quant + tanh
__device__ __forceinline__ float bhi(unsigned u) { return __builtin_bit_cast(float, u); }

__device__ __forceinline__ i32x8 mk8(uint4 a, uint4 b) {
    i32x8 v;
    v[0] = (int)a.x; v[1] = (int)a.y; v[2] = (int)a.z; v[3] = (int)a.w;
    v[4] = (int)b.x; v[5] = (int)b.y; v[6] = (int)b.z; v[7] = (int)b.w;
    return v;
}

// async global->LDS DMA, 16B/lane. LDS destination = wave-uniform base + lane*16.
__device__ __forceinline__ void gld_lds16(const void* g, void* l) {
    __builtin_amdgcn_global_load_lds(
        (const __attribute__((address_space(1))) void*)g,
        (__attribute__((address_space(3))) void*)l, 16, 0, 0);
}

// ---------------- Phase 1: lt fp32->bf16 row-major; rt fp32->fp8 TILED ----------------
// rtf tiled layout: element o (16B) with o = ((((b*4+kk)*16+g)*2+h)*64+lane):
//   holds rt[b][s = g*16 + (lane&15)][d = kk*128 + (lane>>4)*32 + h*16 .. +16] as fp8.
__global__ __launch_bounds__(256)
void cast_inputs(const float* __restrict__ lt, const float* __restrict__ rt,
                 unsigned short* __restrict__ ltb, unsigned char* __restrict__ rtf)
{
    const int bid = (int)blockIdx.x;
    if (bid < 2048) {
        size_t base = ((size_t)bid * 256 + threadIdx.x) * 8;
        float4 a = *(const float4*)(lt + base);
        float4 b = *(const float4*)(lt + base + 4);
        uint4 w;
        w.x = pack_bf16(a.x, a.y);
        w.y = pack_bf16(a.z, a.w);
        w.z = pack_bf16(b.x, b.y);
        w.w = pack_bf16(b.z, b.w);
        *(uint4*)(ltb + base) = w;
    } else {
        const unsigned o = (unsigned)(bid - 2048) * 256 + threadIdx.x;  // 0..262143
        const int lane = o & 63;
        const int h    = (o >> 6) & 1;
        const int g    = (o >> 7) & 15;
        const int kk   = (o >> 11) & 3;
        const int b    = o >> 13;
        const int s    = g * 16 + (lane & 15);
        const int d0   = kk * 128 + (lane >> 4) * 32 + h * 16;
        const float* p = rt + ((size_t)b * TT + s) * DD + d0;
        float4 x0 = *(const float4*)p;
        float4 x1 = *(const float4*)(p + 4);
        float4 x2 = *(const float4*)(p + 8);
        float4 x3 = *(const float4*)(p + 12);
        uint4 w;
        w.x = pk4_fp8(x0.x, x0.y, x0.z, x0.w);
        w.y = pk4_fp8(x1.x, x1.y, x1.z, x1.w);
        w.z = pk4_fp8(x2.x, x2.y, x2.z, x2.w);
        w.w = pk4_fp8(x3.x, x3.y, x3.z, x3.w);
        *(uint4*)(rtf + (size_t)o * 16) = w;
    }
}

// ---------------- Main: 64t x 256s, MX fp8 K=128, barrier-free K-loop ----------------
__global__ __launch_bounds__(256, 3)
void mp_match_mx(const unsigned short* __restrict__ ltb, const unsigned char* __restrict__ rtf,
                 const float* __restrict__ km, float* __restrict__ out)
{
    __shared__ __attribute__((aligned(16))) uint4 Ash[BM * 33];          // 33.8 KB (R10 layout)
    __shared__ __attribute__((aligned(16))) unsigned char Bsh[2][8192];  // 16 KB  (dbuf s=64 slices)
    __shared__ __attribute__((aligned(16))) float maxbuf[4][BM];         // 1 KB

    // XCD swizzle: flat%8 == XCD; b%8 == XCD.
    const int f  = blockIdx.x;           // 0..2559
    const int c8 = f & 7;
    const int i  = f >> 3;               // 0..319
    const int b  = c8 + 8 * (i / 80);    // 0..31
    const int j  = i % 80;
    const int m  = j >> 2;               // 0..19
    const int t0 = (j & 3) * BM;         // 0,64,128,192

    const int tid  = threadIdx.x;
    const int w    = tid >> 6;           // wave id
    const int lane = tid & 63;
    const int l15  = lane & 15;
    const int l4   = lane >> 4;          // k-block-of-32 within K=128

    const unsigned short* ltB = ltb + ((size_t)b * TT + t0) * DD;
    const unsigned char*  rtT = rtf + (size_t)b * (TT * DD);   // tiled, 131072 B per b
    const float*          kmp = km  + (size_t)m * DD;

    // step u = kk*4 + q covers (K-bytes kk*128..+128, s-range q*64..+64).
    // wave w stages & consumes rows s = q*64 + w*16 + l15 -> tiled group g = q*4+w.
    auto stageB = [&](int u) {
        const int kk = u >> 2, q = u & 3;
        const unsigned char* g = rtT + kk * 32768 + (q * 4 + w) * 2048 + lane * 16;
        unsigned char* l = &Bsh[u & 1][w * 2048];
        gld_lds16(g, l);                  // h=0: d-bytes +0..16
        gld_lds16(g + 1024, l + 1024);    // h=1: d-bytes +16..32
    };

    stageB(0);   // in flight under the whole A conversion

    // ---- A staging: thread -> chunk-col cc (d = cc*16..+16), rows r0..r0+8 (R10 scheme).
    const int cc = tid & 31, r0 = (tid >> 5) * 8;
    const float4 kA = *(const float4*)(kmp + cc * 16);
    const float4 kB = *(const float4*)(kmp + cc * 16 + 4);
    const float4 kC = *(const float4*)(kmp + cc * 16 + 8);
    const float4 kD = *(const float4*)(kmp + cc * 16 + 12);
#pragma unroll
    for (int r = 0; r < 8; ++r) {
        const unsigned short* src = ltB + (size_t)(r0 + r) * DD + cc * 16;
        uint4 h0 = *(const uint4*)src;        // bf16 d..d+7
        uint4 h1 = *(const uint4*)(src + 8);  // bf16 d+8..d+15
        uint4 o;
        o.x = pk4_fp8(blo(h0.x) * kA.x, bhi(h0.x) * kA.y, blo(h0.y) * kA.z, bhi(h0.y) * kA.w);
        o.y = pk4_fp8(blo(h0.z) * kB.x, bhi(h0.z) * kB.y, blo(h0.w) * kB.z, bhi(h0.w) * kB.w);
        o.z = pk4_fp8(blo(h1.x) * kC.x, bhi(h1.x) * kC.y, blo(h1.y) * kC.z, bhi(h1.y) * kC.w);
        o.w = pk4_fp8(blo(h1.z) * kD.x, bhi(h1.z) * kD.y, blo(h1.w) * kD.z, bhi(h1.w) * kD.w);
        Ash[(r0 + r) * 33 + cc] = o;
    }
    __syncthreads();   // Ash visible to all waves; also drains stage(0) (vmcnt(0) before barrier)

    f32x4 acc[4][4] = {};   // [ii][q]: t = t0 + ii*16 + ..., s = q*64 + w*16 + ...
    i32x8 av[4];

#pragma unroll
    for (int u = 0; u < 16; ++u) {
        const int kk = u >> 2, q = u & 3;
        if (u + 1 < 16) {
            stageB(u + 1);   // 2 DMA insts into Bsh[(u+1)&1]; safe: last read of that
                             // buffer (step u-1) was lgkm-waited before its MFMAs.
            // counted wait: in-flight = stage(u)'s 2 + stage(u+1)'s 2; leave the newest 2.
            asm volatile("s_waitcnt vmcnt(2)" ::: "memory");
        } else {
            asm volatile("s_waitcnt vmcnt(0)" ::: "memory");
        }
        if (q == 0) {
            // A frags for this kk: row = ii*16 + l15, chunks kk*8 + l4*2 (+1) — R10 layout.
#pragma unroll
            for (int ii = 0; ii < 4; ++ii) {
                const int base = (ii * 16 + l15) * 33 + kk * 8 + l4 * 2;
                av[ii] = mk8(Ash[base], Ash[base + 1]);
            }
        }
        // B frag: lane-linear in the staged slice -> conflict-free ds_read_b128 pair.
        const uint4* bp = (const uint4*)&Bsh[u & 1][w * 2048];
        i32x8 bv = mk8(bp[lane], bp[64 + lane]);
#pragma unroll
        for (int ii = 0; ii < 4; ++ii)
            acc[ii][q] = __builtin_amdgcn_mfma_scale_f32_16x16x128_f8f6f4(
                av[ii], bv, acc[ii][q], 0, 0, 0, 127, 0, 127);  // fmt=fp8, scales=1.0
    }

    // ---- Epilogue: max over s. C layout: col(s)=lane&15, row(t)=(lane>>4)*4+reg.
#pragma unroll
    for (int ii = 0; ii < 4; ++ii) {
        f32x4 v = acc[ii][0];
#pragma unroll
        for (int q = 1; q < 4; ++q) {
            v.x = fmaxf(v.x, acc[ii][q].x);
            v.y = fmaxf(v.y, acc[ii][q].y);
            v.z = fmaxf(v.z, acc[ii][q].z);
            v.w = fmaxf(v.w, acc[ii][q].w);
        }
#pragma unroll
        for (int off = 1; off < 16; off <<= 1) {
            v.x = fmaxf(v.x, __shfl_xor(v.x, off, 64));
            v.y = fmaxf(v.y, __shfl_xor(v.y, off, 64));
            v.z = fmaxf(v.z, __shfl_xor(v.z, off, 64));
            v.w = fmaxf(v.w, __shfl_xor(v.w, off, 64));
        }
        if (l15 == 0)
            *(f32x4*)&maxbuf[w][ii * 16 + l4 * 4] = v;
    }
    __syncthreads();
    if (tid < BM) {
        float v = fmaxf(fmaxf(maxbuf[0][tid], maxbuf[1][tid]),
                        fmaxf(maxbuf[2][tid], maxbuf[3][tid]));
        out[((size_t)b * TT + t0 + tid) * NM + m] = tanhf(v);
    }
}

// ---------------- R1 fallback (no workspace): bf16 MFMA, fp32 register staging ----------------
typedef short bf16x8 __attribute__((ext_vector_type(8)));

__global__ __launch_bounds__(256, 2)
void mp_match_kernel(const float* __restrict__ lt, const float* __restrict__ rt,
                     const float* __restrict__ km, float* __restrict__ out)
{
    __shared__ __attribute__((aligned(16))) unsigned short Ash[2][4][128][8];
    __shared__ __attribute__((aligned(16))) unsigned short Bsh2[2][4][256][8];
    __shared__ __attribute__((aligned(16))) float maxbuf[2][128];

    const int ttile = blockIdx.x, m = blockIdx.y, b = blockIdx.z;
    const int t0 = ttile * 128;
    const int tid = threadIdx.x, wave = tid >> 6, lane = tid & 63;
    const int l15 = lane & 15, l4 = lane >> 4;
    const int wt = (wave & 1) * 64, wsi = wave >> 1;

    const float* ltp = lt + ((size_t)b * TT + t0) * DD;
    const float* rtp = rt + (size_t)b * TT * DD;
    const float* kmp = km + (size_t)m * DD;
    const int a_t = tid >> 1, a_h = tid & 1;

    f32x4 acc[4][8] = {};

    auto stage = [&](int kk, int buf) {
        const int d0 = kk * 32;
        const float* ap = ltp + (size_t)a_t * DD + d0 + a_h * 16;
        const float* kp = kmp + d0 + a_h * 16;
#pragma unroll
        for (int q = 0; q < 2; ++q) {
            float4 x0 = *(const float4*)(ap + q * 8);
            float4 x1 = *(const float4*)(ap + q * 8 + 4);
            float4 k0 = *(const float4*)(kp + q * 8);
            float4 k1 = *(const float4*)(kp + q * 8 + 4);
            uint4 wv;
            wv.x = pack_bf16(x0.x * k0.x, x0.y * k0.y);
            wv.y = pack_bf16(x0.z * k0.z, x0.w * k0.w);
            wv.z = pack_bf16(x1.x * k1.x, x1.y * k1.y);
            wv.w = pack_bf16(x1.z * k1.z, x1.w * k1.w);
            *(uint4*)&Ash[buf][a_h * 2 + q][a_t][0] = wv;
        }
        const float* bp = rtp + (size_t)tid * DD + d0;
#pragma unroll
        for (int p = 0; p < 4; ++p) {
            float4 y0 = *(const float4*)(bp + p * 8);
            float4 y1 = *(const float4*)(bp + p * 8 + 4);
            uint4 wv;
            wv.x = pack_bf16(y0.x, y0.y);
            wv.y = pack_bf16(y0.z, y0.w);
            wv.z = pack_bf16(y1.x, y1.y);
            wv.w = pack_bf16(y1.z, y1.w);
            *(uint4*)&Bsh2[buf][p][tid][0] = wv;
        }
    };

    stage(0, 0);
    for (int kk = 0; kk < 16; ++kk) {
        const int buf = kk & 1;
        __syncthreads();
        bf16x8 af[4], bfv[8];
#pragma unroll
        for (int i2 = 0; i2 < 4; ++i2)
            af[i2] = *(const bf16x8*)&Ash[buf][l4][wt + i2 * 16 + l15][0];
#pragma unroll
        for (int j2 = 0; j2 < 8; ++j2)
            bfv[j2] = *(const bf16x8*)&Bsh2[buf][l4][wsi * 128 + j2 * 16 + l15][0];
        if (kk + 1 < 16) stage(kk + 1, buf ^ 1);
#pragma unroll
        for (int i2 = 0; i2 < 4; ++i2)
#pragma unroll
            for (int j2 = 0; j2 < 8; ++j2)
                acc[i2][j2] = __builtin_amdgcn_mfma_f32_16x16x32_bf16(af[i2], bfv[j2], acc[i2][j2], 0, 0, 0);
    }
#pragma unroll
    for (int i2 = 0; i2 < 4; ++i2) {
        f32x4 v = acc[i2][0];
#pragma unroll
        for (int j2 = 1; j2 < 8; ++j2) {
            v.x = fmaxf(v.x, acc[i2][j2].x); v.y = fmaxf(v.y, acc[i2][j2].y);
            v.z = fmaxf(v.z, acc[i2][j2].z); v.w = fmaxf(v.w, acc[i2][j2].w);
        }
#pragma unroll
        for (int off = 1; off < 16; off <<= 1) {
            v.x = fmaxf(v.x, __shfl_xor(v.x, off, 64));
            v.y = fmaxf(v.y, __shfl_xor(v.y, off, 64));
            v.z = fmaxf(v.z, __shfl_xor(v.z, off, 64));
            v.w = fmaxf(v.w, __shfl_xor(v.w, off, 64));
        }
        if (l15 == 0) *(f32x4*)&maxbuf[wsi][wt + i2 * 16 + l4 * 4] = v;
    }
    __syncthreads();
    if (tid < 128) {
        float v = fmaxf(maxbuf[0][tid], maxbuf[1][tid]);
        out[((size_t)b * TT + t0 + tid) * NM + m] = tanhf(v);
    }
}

extern "C" void kernel_launch(void* const* d_in, const int* in_sizes, int n_in,
                              void* d_out, int out_size, void* d_ws, size_t ws_size,
                              hipStream_t stream) {
    const float* lt  = (const float*)d_in[0];   // (32,256,512) fp32
    const float* rt  = (const float*)d_in[1];   // (32,256,512) fp32
    const float* km  = (const float*)d_in[2];   // (20,512) fp32
    float*       out = (float*)d_out;           // (32,256,20) fp32

    const size_t elems = (size_t)NB * TT * DD;                 // 4,194,304
    const size_t ltbB  = elems * sizeof(unsigned short);       // 8.39 MB bf16
    const size_t rtfB  = elems;                                // 4.19 MB fp8 (tiled)

    if (ws_size >= ltbB + rtfB) {                              // 12.6 MB
        unsigned short* ltb = (unsigned short*)d_ws;
        unsigned char*  rtf = (unsigned char*)((char*)d_ws + ltbB);
        // 2048 blocks lt->bf16 (8 elem/thread) + 1024 blocks rt->fp8 tiled (16 elem/thread)
        cast_inputs<<<3072, 256, 0, stream>>>(lt, rt, ltb, rtf);
        mp_match_mx<<<2560, 256, 0, stream>>>(ltb, rtf, km, out);
    } else {
        mp_match_kernel<<<dim3(2, NM, NB), 256, 0, stream>>>(lt, rt, km, out);
    }
}

// Round 2
// 110.376 us; speedup vs baseline: 1.1220x; 1.0556x over previous
//
#include <hip/hip_runtime.h>

// MpMaxPoolingMatch: out[b,t,m] = tanh( max_s sum_d lt[b,t,d]*km[m,d]*rt[b,s,d] )
// B=32, T=256, D=512, MP=20.
// R12: B operand global->VGPR ring, no LDS staging for B, no inline-asm waits.
// R11 post-mortem: barrier-free LDS B with vmcnt(2) was only 1-step-deep
// (~150cy lead vs ~250cy L2 latency) and the per-step asm "memory" clobbers
// pinned the scheduler (m141 lesson) -> per-step chain = vmcnt stall + 120cy
// ds_read latency + 139cy MFMA ~= 2.5x the MFMA floor. Match stuck ~45us.
// Changes vs R11:
//  * rtf tiled layout retained: per (kk,q,wave) the B-fragment is TWO coalesced
//    1KB wave loads at rtB0 + u*8192 (+1024). Load straight into a 4-slot VGPR
//    ring (8 regs/slot), prefetch lead 3 (~420cy cover). Compiler emits counted
//    vmcnt on its own; register WAR on the ring enforces correctness.
//  * lt->bf16 pre-pass DELETED: A-staging reads lt fp32 directly (2KB/row/wave
//    coalesced, L2-resident across the 20 m-blocks per b), fuses *km + fp8
//    convert. One fewer rounding step. Cast kernel is now rt-only (~7us).
//  * LDS = Ash 33.8K + maxbuf 1K = 34.8K; VGPR ~155 -> 3 waves/SIMD (12/CU).
// MFMA shape/byte order/scales (e8m0=127) and epilogue identical to R10/R11.

constexpr int TT = 256;   // T
constexpr int DD = 512;   // D
constexpr int NM = 20;    // MP
constexpr int NB = 32;    // B
constexpr int BM = 64;    // t-tile

typedef float f32x4 __attribute__((ext_vector_type(4)));
typedef int   i32x8 __attribute__((ext_vector_type(8)));

__device__ __forceinline__ unsigned pack_bf16(float lo, float hi) {
    unsigned ulo = __builtin_bit_cast(unsigned, lo);
    unsigned uhi = __builtin_bit_cast(unsigned, hi);
    return (ulo >> 16) | (uhi & 0xFFFF0000u);
}

// 4 fp32 -> 4 fp8 (e4m3, packed dword)
__device__ __forceinline__ unsigned pk4_fp8(float a, float b, float c, float d) {
    unsigned r = __builtin_amdgcn_cvt_pk_fp8_f32(a, b, 0, false);
    return __builtin_amdgcn_cvt_pk_fp8_f32(c, d, r, true);
}

__device__ __forceinline__ i32x8 mk8(uint4 a, uint4 b) {
    i32x8 v;
    v[0] = (int)a.x; v[1] = (int)a.y; v[2] = (int)a.z; v[3] = (int)a.w;
    v[4] = (int)b.x; v[5] = (int)b.y; v[6] = (int)b.z; v[7] = (int)b.w;
    return v;
}

// ---------------- Phase 1: rt fp32 -> fp8 TILED (rt only; lt read raw by main) --------
// rtf tiled layout: 16B element o = ((((b*4+kk)*16+g)*2+h)*64+lane):
//   holds rt[b][s = g*16 + (lane&15)][d = kk*128 + (lane>>4)*32 + h*16 .. +16] as fp8.
__global__ __launch_bounds__(256)
void cast_rt(const float* __restrict__ rt, unsigned char* __restrict__ rtf)
{
    const unsigned o = (unsigned)blockIdx.x * 256 + threadIdx.x;  // 0..262143
    const int lane = o & 63;
    const int h    = (o >> 6) & 1;
    const int g    = (o >> 7) & 15;
    const int kk   = (o >> 11) & 3;
    const int b    = o >> 13;
    const int s    = g * 16 + (lane & 15);
    const int d0   = kk * 128 + (lane >> 4) * 32 + h * 16;
    const float* p = rt + ((size_t)b * TT + s) * DD + d0;
    float4 x0 = *(const float4*)p;
    float4 x1 = *(const float4*)(p + 4);
    float4 x2 = *(const float4*)(p + 8);
    float4 x3 = *(const float4*)(p + 12);
    uint4 w;
    w.x = pk4_fp8(x0.x, x0.y, x0.z, x0.w);
    w.y = pk4_fp8(x1.x, x1.y, x1.z, x1.w);
    w.z = pk4_fp8(x2.x, x2.y, x2.z, x2.w);
    w.w = pk4_fp8(x3.x, x3.y, x3.z, x3.w);
    *(uint4*)(rtf + (size_t)o * 16) = w;
}

// ---------------- Main: 64t x 256s, MX fp8 K=128, B in VGPR ring ----------------
__global__ __launch_bounds__(256, 3)
void mp_match_mx(const float* __restrict__ lt, const unsigned char* __restrict__ rtf,
                 const float* __restrict__ km, float* __restrict__ out)
{
    __shared__ __attribute__((aligned(16))) uint4 Ash[BM * 33];   // 33.8 KB (stride 33)
    __shared__ __attribute__((aligned(16))) float maxbuf[4][BM];  // 1 KB

    // XCD swizzle: flat%8 == XCD; b%8 == XCD.
    const int f  = blockIdx.x;           // 0..2559
    const int c8 = f & 7;
    const int i  = f >> 3;               // 0..319
    const int b  = c8 + 8 * (i / 80);    // 0..31
    const int j  = i % 80;
    const int m  = j >> 2;               // 0..19
    const int t0 = (j & 3) * BM;         // 0,64,128,192

    const int tid  = threadIdx.x;
    const int w    = tid >> 6;           // wave id = s-quarter owner
    const int lane = tid & 63;
    const int l15  = lane & 15;
    const int l4   = lane >> 4;

    const float*         ltB  = lt  + ((size_t)b * TT + t0) * DD;
    const float*         kmp  = km  + (size_t)m * DD;
    // step u = kk*4+q: wave w's B-frag lives at rtB0 + u*8192 (h=0) and +1024 (h=1).
    const unsigned char* rtB0 = rtf + (size_t)b * (TT * DD) + w * 2048 + lane * 16;

    uint4 ring[4][2];
    auto loadB = [&](int u) {
        const unsigned char* p = rtB0 + u * 8192;
        ring[u & 3][0] = *(const uint4*)p;
        ring[u & 3][1] = *(const uint4*)(p + 1024);
    };

    // 3-deep prologue: in flight under the whole A conversion.
    loadB(0); loadB(1); loadB(2);

    // ---- A staging: thread -> chunk-col cc (d = cc*16..+16), rows r0..r0+8.
    // Reads lt fp32 directly (2KB contiguous per row per wave), fuses *km + fp8.
    const int cc = tid & 31, r0 = (tid >> 5) * 8;
    const float4 kA = *(const float4*)(kmp + cc * 16);
    const float4 kB = *(const float4*)(kmp + cc * 16 + 4);
    const float4 kC = *(const float4*)(kmp + cc * 16 + 8);
    const float4 kD = *(const float4*)(kmp + cc * 16 + 12);
#pragma unroll
    for (int r = 0; r < 8; ++r) {
        const float* src = ltB + (size_t)(r0 + r) * DD + cc * 16;
        float4 x0 = *(const float4*)src;
        float4 x1 = *(const float4*)(src + 4);
        float4 x2 = *(const float4*)(src + 8);
        float4 x3 = *(const float4*)(src + 12);
        uint4 o;
        o.x = pk4_fp8(x0.x * kA.x, x0.y * kA.y, x0.z * kA.z, x0.w * kA.w);
        o.y = pk4_fp8(x1.x * kB.x, x1.y * kB.y, x1.z * kB.z, x1.w * kB.w);
        o.z = pk4_fp8(x2.x * kC.x, x2.y * kC.y, x2.z * kC.z, x2.w * kC.w);
        o.w = pk4_fp8(x3.x * kD.x, x3.y * kD.y, x3.z * kD.z, x3.w * kD.w);
        Ash[(r0 + r) * 33 + cc] = o;
    }
    __syncthreads();   // the ONLY pre-epilogue barrier

    f32x4 acc[4][4] = {};   // [ii][q]: t = t0+ii*16+..., s = q*64 + w*16 + ...
    i32x8 av[4];

#pragma unroll
    for (int u = 0; u < 16; ++u) {
        const int kk = u >> 2, q = u & 3;
        if (u + 3 < 16) loadB(u + 3);   // ring WAR keeps this honest; lead = 3 steps
        if (q == 0) {
            // A frags for this kk: row = ii*16 + l15, chunks kk*8 + l4*2 (+1).
#pragma unroll
            for (int ii = 0; ii < 4; ++ii) {
                const int base = (ii * 16 + l15) * 33 + kk * 8 + l4 * 2;
                av[ii] = mk8(Ash[base], Ash[base + 1]);
            }
        }
        i32x8 bv = mk8(ring[u & 3][0], ring[u & 3][1]);
#pragma unroll
        for (int ii = 0; ii < 4; ++ii)
            acc[ii][q] = __builtin_amdgcn_mfma_scale_f32_16x16x128_f8f6f4(
                av[ii], bv, acc[ii][q], 0, 0, 0, 127, 0, 127);  // fmt=fp8, scales=1.0
    }

    // ---- Epilogue: max over s. C layout: col(s)=lane&15, row(t)=(lane>>4)*4+reg.
#pragma unroll
    for (int ii = 0; ii < 4; ++ii) {
        f32x4 v = acc[ii][0];
#pragma unroll
        for (int q = 1; q < 4; ++q) {
            v.x = fmaxf(v.x, acc[ii][q].x);
            v.y = fmaxf(v.y, acc[ii][q].y);
            v.z = fmaxf(v.z, acc[ii][q].z);
            v.w = fmaxf(v.w, acc[ii][q].w);
        }
#pragma unroll
        for (int off = 1; off < 16; off <<= 1) {
            v.x = fmaxf(v.x, __shfl_xor(v.x, off, 64));
            v.y = fmaxf(v.y, __shfl_xor(v.y, off, 64));
            v.z = fmaxf(v.z, __shfl_xor(v.z, off, 64));
            v.w = fmaxf(v.w, __shfl_xor(v.w, off, 64));
        }
        if (l15 == 0)
            *(f32x4*)&maxbuf[w][ii * 16 + l4 * 4] = v;
    }
    __syncthreads();
    if (tid < BM) {
        float v = fmaxf(fmaxf(maxbuf[0][tid], maxbuf[1][tid]),
                        fmaxf(maxbuf[2][tid], maxbuf[3][tid]));
        out[((size_t)b * TT + t0 + tid) * NM + m] = tanhf(v);
    }
}

// ---------------- R1 fallback (no workspace): bf16 MFMA, fp32 register staging ----------------
typedef short bf16x8 __attribute__((ext_vector_type(8)));

__global__ __launch_bounds__(256, 2)
void mp_match_kernel(const float* __restrict__ lt, const float* __restrict__ rt,
                     const float* __restrict__ km, float* __restrict__ out)
{
    __shared__ __attribute__((aligned(16))) unsigned short Ash[2][4][128][8];
    __shared__ __attribute__((aligned(16))) unsigned short Bsh2[2][4][256][8];
    __shared__ __attribute__((aligned(16))) float maxbuf[2][128];

    const int ttile = blockIdx.x, m = blockIdx.y, b = blockIdx.z;
    const int t0 = ttile * 128;
    const int tid = threadIdx.x, wave = tid >> 6, lane = tid & 63;
    const int l15 = lane & 15, l4 = lane >> 4;
    const int wt = (wave & 1) * 64, wsi = wave >> 1;

    const float* ltp = lt + ((size_t)b * TT + t0) * DD;
    const float* rtp = rt + (size_t)b * TT * DD;
    const float* kmp = km + (size_t)m * DD;
    const int a_t = tid >> 1, a_h = tid & 1;

    f32x4 acc[4][8] = {};

    auto stage = [&](int kk, int buf) {
        const int d0 = kk * 32;
        const float* ap = ltp + (size_t)a_t * DD + d0 + a_h * 16;
        const float* kp = kmp + d0 + a_h * 16;
#pragma unroll
        for (int q = 0; q < 2; ++q) {
            float4 x0 = *(const float4*)(ap + q * 8);
            float4 x1 = *(const float4*)(ap + q * 8 + 4);
            float4 k0 = *(const float4*)(kp + q * 8);
            float4 k1 = *(const float4*)(kp + q * 8 + 4);
            uint4 wv;
            wv.x = pack_bf16(x0.x * k0.x, x0.y * k0.y);
            wv.y = pack_bf16(x0.z * k0.z, x0.w * k0.w);
            wv.z = pack_bf16(x1.x * k1.x, x1.y * k1.y);
            wv.w = pack_bf16(x1.z * k1.z, x1.w * k1.w);
            *(uint4*)&Ash[buf][a_h * 2 + q][a_t][0] = wv;
        }
        const float* bp = rtp + (size_t)tid * DD + d0;
#pragma unroll
        for (int p = 0; p < 4; ++p) {
            float4 y0 = *(const float4*)(bp + p * 8);
            float4 y1 = *(const float4*)(bp + p * 8 + 4);
            uint4 wv;
            wv.x = pack_bf16(y0.x, y0.y);
            wv.y = pack_bf16(y0.z, y0.w);
            wv.z = pack_bf16(y1.x, y1.y);
            wv.w = pack_bf16(y1.z, y1.w);
            *(uint4*)&Bsh2[buf][p][tid][0] = wv;
        }
    };

    stage(0, 0);
    for (int kk = 0; kk < 16; ++kk) {
        const int buf = kk & 1;
        __syncthreads();
        bf16x8 af[4], bfv[8];
#pragma unroll
        for (int i2 = 0; i2 < 4; ++i2)
            af[i2] = *(const bf16x8*)&Ash[buf][l4][wt + i2 * 16 + l15][0];
#pragma unroll
        for (int j2 = 0; j2 < 8; ++j2)
            bfv[j2] = *(const bf16x8*)&Bsh2[buf][l4][wsi * 128 + j2 * 16 + l15][0];
        if (kk + 1 < 16) stage(kk + 1, buf ^ 1);
#pragma unroll
        for (int i2 = 0; i2 < 4; ++i2)
#pragma unroll
            for (int j2 = 0; j2 < 8; ++j2)
                acc[i2][j2] = __builtin_amdgcn_mfma_f32_16x16x32_bf16(af[i2], bfv[j2], acc[i2][j2], 0, 0, 0);
    }
#pragma unroll
    for (int i2 = 0; i2 < 4; ++i2) {
        f32x4 v = acc[i2][0];
#pragma unroll
        for (int j2 = 1; j2 < 8; ++j2) {
            v.x = fmaxf(v.x, acc[i2][j2].x); v.y = fmaxf(v.y, acc[i2][j2].y);
            v.z = fmaxf(v.z, acc[i2][j2].z); v.w = fmaxf(v.w, acc[i2][j2].w);
        }
#pragma unroll
        for (int off = 1; off < 16; off <<= 1) {
            v.x = fmaxf(v.x, __shfl_xor(v.x, off, 64));
            v.y = fmaxf(v.y, __shfl_xor(v.y, off, 64));
            v.z = fmaxf(v.z, __shfl_xor(v.z, off, 64));
            v.w = fmaxf(v.w, __shfl_xor(v.w, off, 64));
        }
        if (l15 == 0) *(f32x4*)&maxbuf[wsi][wt + i2 * 16 + l4 * 4] = v;
    }
    __syncthreads();
    if (tid < 128) {
        float v = fmaxf(maxbuf[0][tid], maxbuf[1][tid]);
        out[((size_t)b * TT + t0 + tid) * NM + m] = tanhf(v);
    }
}

extern "C" void kernel_launch(void* const* d_in, const int* in_sizes, int n_in,
                              void* d_out, int out_size, void* d_ws, size_t ws_size,
                              hipStream_t stream) {
    const float* lt  = (const float*)d_in[0];   // (32,256,512) fp32
    const float* rt  = (const float*)d_in[1];   // (32,256,512) fp32
    const float* km  = (const float*)d_in[2];   // (20,512) fp32
    float*       out = (float*)d_out;           // (32,256,20) fp32

    const size_t elems = (size_t)NB * TT * DD;  // 4,194,304
    const size_t rtfB  = elems;                 // 4.19 MB fp8 (tiled)

    if (ws_size >= rtfB) {
        unsigned char* rtf = (unsigned char*)d_ws;
        cast_rt<<<1024, 256, 0, stream>>>(rt, rtf);          // 16 elem/thread tiled fp8
        mp_match_mx<<<2560, 256, 0, stream>>>(lt, rtf, km, out);
    } else {
        mp_match_kernel<<<dim3(2, NM, NB), 256, 0, stream>>>(lt, rt, km, out);
    }
}